// Round 9
// baseline (107.646 us; speedup 1.0000x reference)
//
#include <hip/hip_runtime.h>
#include <hip/hip_fp16.h>

#define BATCH   512
#define IN_DIM  16384
#define KNN     32
#define NBLOCKS 2048
#define SLOTS   256        // per-chunk slots; 8*SLOTS == NBLOCKS (pigeonhole)

typedef __attribute__((ext_vector_type(4))) _Float16 half4v;

#define N0 (8192 * KNN)
#define N1 (4096 * KNN)
#define N2 (2048 * KNN)

// ---------------------------------------------------------------------------
// Real XCD id from hardware (verified MI355X: 0..7).
// ---------------------------------------------------------------------------
__device__ __forceinline__ int xcd_id() {
    int x;
    asm volatile("s_getreg_b32 %0, hwreg(HW_REG_XCC_ID)" : "=s"(x));
    return x & 7;
}

// ---------------------------------------------------------------------------
// Prep: pack (knn:int32, w:fp32) -> uint32 (low16 idx, high16 fp16-bits).
// Native-dword s_load path, halved scalar working set (proven neutral-safe R8).
// ---------------------------------------------------------------------------
__global__ __launch_bounds__(256) void prep_k(const int* __restrict__ k0,
                                              const float* __restrict__ w0,
                                              const int* __restrict__ k1,
                                              const float* __restrict__ w1,
                                              const int* __restrict__ k2,
                                              const float* __restrict__ w2,
                                              unsigned int* __restrict__ po) {
    const int t = blockIdx.x * 256 + threadIdx.x;
    int idx; float wv;
    if (t < N0) {
        idx = k0[t];            wv = w0[t];
    } else if (t < N0 + N1) {
        idx = k1[t - N0];       wv = w1[t - N0];
    } else if (t < N0 + N1 + N2) {
        idx = k2[t - N0 - N1];  wv = w2[t - N0 - N1];
    } else {
        return;
    }
    const unsigned short hb = __builtin_bit_cast(unsigned short, (_Float16)wv);
    po[t] = (unsigned int)(unsigned short)idx | ((unsigned int)hb << 16);
}

// ---------------------------------------------------------------------------
// Transpose x (BATCH, IN_DIM) fp32 -> xt (IN_DIM, BATCH) fp16.
// ---------------------------------------------------------------------------
__global__ __launch_bounds__(256) void transpose_h(const float* __restrict__ in,
                                                   _Float16* __restrict__ out) {
    __shared__ float tile[32][33];
    const int bx = blockIdx.x * 32;          // IN_DIM base
    const int by = blockIdx.y * 32;          // BATCH base
    const int tx = threadIdx.x & 31;
    const int ty = threadIdx.x >> 5;         // 0..7
#pragma unroll
    for (int j = 0; j < 32; j += 8)
        tile[ty + j][tx] = in[(size_t)(by + ty + j) * IN_DIM + bx + tx];
    __syncthreads();
    const int r = threadIdx.x >> 3;          // 0..31  (local d)
    const int c = (threadIdx.x & 7) * 4;     // local batch base
    half4v h;
    h[0] = (_Float16)tile[c + 0][r];
    h[1] = (_Float16)tile[c + 1][r];
    h[2] = (_Float16)tile[c + 2][r];
    h[3] = (_Float16)tile[c + 3][r];
    *(half4v*)(out + (size_t)(bx + r) * BATCH + by + c) = h;
}

// ---------------------------------------------------------------------------
// LCN layer, XCC_ID-static chunk assignment, ONE atomic claim per block.
// 2048 blocks; block claims slot s of its own XCD's chunk counter (spills to
// neighbor chunks only when full -- with NBLOCKS == 8*SLOTS every slot is
// claimed exactly once, so coverage and determinism hold for ANY dispatch).
// Block then computes FPB contiguous features for its 64-wide batch chunk:
// the chunk's input slab (<=2MB) + packed (<=1MB) stays in the claiming
// XCD's own L2 (XCD L2s cache what their own CUs read).
// Inner loop == R8 (scalar packed s_loads, 128B/wave gathers, fp32 acc).
// ---------------------------------------------------------------------------
template<int DOUT>
__global__ __launch_bounds__(256) void lcn_xs(const _Float16* __restrict__ xt,
                                              const unsigned int* __restrict__ packed,
                                              const float* __restrict__ bias,
                                              _Float16* __restrict__ yt,
                                              int* __restrict__ ctrs) {
    constexpr int FPB = DOUT / SLOTS;   // features per block
    constexpr int FPW = FPB / 4;        // features per wave
    __shared__ int s_claim;
    if (threadIdx.x == 0) {
        const int x = xcd_id();
        int claim = -1;
        for (int q = 0; q < 8; ++q) {
            const int c = (x + q) & 7;
            int* p = ctrs + c * 32;                  // 128B-spaced counters
            if (__hip_atomic_load(p, __ATOMIC_RELAXED,
                                  __HIP_MEMORY_SCOPE_AGENT) >= SLOTS)
                continue;                            // chunk full, try next
            const int v = atomicAdd(p, 1);
            if (v < SLOTS) { claim = (c << 16) | v; break; }
        }
        s_claim = claim;
    }
    __syncthreads();
    const int claim = __builtin_amdgcn_readfirstlane(s_claim);
    if (claim < 0) return;                           // unreachable (pigeonhole)
    const int chunk = claim >> 16;
    const int slot  = claim & 0xffff;
    const int lane  = threadIdx.x & 63;
    const int wv    = __builtin_amdgcn_readfirstlane(threadIdx.x >> 6);
    const int b     = chunk * 64 + lane;
    const _Float16* xb = xt + b;
    const int dbase = slot * FPB + wv * FPW;
    for (int i = 0; i < FPW; ++i) {
        const int d = dbase + i;
        const unsigned int* kp = packed + (size_t)d * KNN;
        float acc = 0.f;
#pragma unroll
        for (int k = 0; k < KNN; ++k) {
            const unsigned int u = kp[k];            // s_load dword
            const int idx = (int)(u & 0xffffu);
            const _Float16 hw =
                __builtin_bit_cast(_Float16, (unsigned short)(u >> 16));
            acc += (float)hw * (float)xb[(size_t)idx * BATCH];  // 128B/wave
        }
        yt[(size_t)d * BATCH + b] = (_Float16)fmaxf(acc + bias[d], 0.f);
    }
}

// ---------------------------------------------------------------------------
// FC stage 1: partial sums over d-chunks of 256.
// ---------------------------------------------------------------------------
__global__ __launch_bounds__(256) void fc_partial(const _Float16* __restrict__ y2t,
                                                  const float* __restrict__ fcw,
                                                  float* __restrict__ part) {
    const int o  = blockIdx.x & 15;
    const int bh = (blockIdx.x >> 4) & 1;
    const int ch = blockIdx.x >> 5;          // 0..7
    const int b  = bh * 256 + threadIdx.x;
    const int d0 = ch * 256;
    float a0 = 0.f, a1 = 0.f, a2 = 0.f, a3 = 0.f;
#pragma unroll 4
    for (int d = d0; d < d0 + 256; d += 4) {
        a0 += (float)y2t[(size_t)(d + 0) * BATCH + b] * fcw[(d + 0) * 16 + o];
        a1 += (float)y2t[(size_t)(d + 1) * BATCH + b] * fcw[(d + 1) * 16 + o];
        a2 += (float)y2t[(size_t)(d + 2) * BATCH + b] * fcw[(d + 2) * 16 + o];
        a3 += (float)y2t[(size_t)(d + 3) * BATCH + b] * fcw[(d + 3) * 16 + o];
    }
    part[((size_t)b * 16 + o) * 8 + ch] = (a0 + a1) + (a2 + a3);
}

__global__ __launch_bounds__(256) void fc_final(const float* __restrict__ part,
                                                const float* __restrict__ fcb,
                                                float* __restrict__ out) {
    const int t = blockIdx.x * 256 + threadIdx.x;       // 0..8191
    const float4 p0 = *(const float4*)(part + (size_t)t * 8);
    const float4 p1 = *(const float4*)(part + (size_t)t * 8 + 4);
    out[t] = ((p0.x + p0.y) + (p0.z + p0.w)) + ((p1.x + p1.y) + (p1.z + p1.w))
             + fcb[t & 15];
}

extern "C" void kernel_launch(void* const* d_in, const int* in_sizes, int n_in,
                              void* d_out, int out_size, void* d_ws, size_t ws_size,
                              hipStream_t stream) {
    // setup_inputs() order: x, w0,b0,knn0, w1,b1,knn1, w2,b2,knn2, fc_w, fc_b
    const float* x    = (const float*)d_in[0];
    const float* w0   = (const float*)d_in[1];
    const float* b0   = (const float*)d_in[2];
    const int*   knn0 = (const int*)  d_in[3];
    const float* w1   = (const float*)d_in[4];
    const float* b1   = (const float*)d_in[5];
    const int*   knn1 = (const int*)  d_in[6];
    const float* w2   = (const float*)d_in[7];
    const float* b2   = (const float*)d_in[8];
    const int*   knn2 = (const int*)  d_in[9];
    const float* fcw  = (const float*)d_in[10];
    const float* fcb  = (const float*)d_in[11];
    float* out = (float*)d_out;

    // Workspace:
    //   xt   @  0 MB : 16 MB    y0t @ 16 MB : 8 MB
    //   y1t  @ 24 MB :  4 MB    y2t @ 28 MB : 2 MB
    //   part @ 30 MB : 256 KB   packed @ 30.5 MB : 1.75 MB
    //   ctrs @ 33 MB : 3 layers * 8 * 32 ints
    char* ws = (char*)d_ws;
    _Float16*     xt   = (_Float16*)(ws);
    _Float16*     y0t  = (_Float16*)(ws + ((size_t)16 << 20));
    _Float16*     y1t  = (_Float16*)(ws + ((size_t)24 << 20));
    _Float16*     y2t  = (_Float16*)(ws + ((size_t)28 << 20));
    float*        part = (float*)   (ws + ((size_t)30 << 20));
    unsigned int* po   = (unsigned int*)(ws + ((size_t)30 << 20) + ((size_t)512 << 10));
    int*          ctrs = (int*)     (ws + ((size_t)33 << 20));

    hipMemsetAsync(ctrs, 0, 3 * 8 * 32 * sizeof(int), stream);
    prep_k<<<(N0 + N1 + N2 + 255) / 256, 256, 0, stream>>>(knn0, w0, knn1, w1,
                                                           knn2, w2, po);
    transpose_h<<<dim3(IN_DIM / 32, BATCH / 32), 256, 0, stream>>>(x, xt);
    lcn_xs<8192><<<NBLOCKS, 256, 0, stream>>>(xt,  po,           b0, y0t, ctrs);
    lcn_xs<4096><<<NBLOCKS, 256, 0, stream>>>(y0t, po + N0,      b1, y1t, ctrs + 8 * 32);
    lcn_xs<2048><<<NBLOCKS, 256, 0, stream>>>(y1t, po + N0 + N1, b2, y2t, ctrs + 16 * 32);
    fc_partial<<<256, 256, 0, stream>>>(y2t, fcw, part);
    fc_final<<<32, 256, 0, stream>>>(part, fcb, out);
}

// Round 10
// 70.882 us; speedup vs baseline: 1.5187x; 1.5187x over previous
//
#include <hip/hip_runtime.h>
#include <hip/hip_fp16.h>

#define BATCH   512
#define IN_DIM  16384
#define KNN     32

typedef __attribute__((ext_vector_type(4))) _Float16 half4v;
typedef __attribute__((ext_vector_type(2))) _Float16 half2v;

#define N0 (8192 * KNN)
#define N1 (4096 * KNN)
#define N2 (2048 * KNN)
#define NPACK (N0 + N1 + N2)            // 458752 = 1792 * 256
#define TR_BLOCKS (512 * 16)            // transpose tiles
#define PREP_BLOCKS (NPACK / 256)       // 1792

// ---------------------------------------------------------------------------
// Fused: transpose x (fp32 [B,IN] -> fp16 [IN,B]) + pack (knn,w) -> uint32.
// Blocks [0, 8192): transpose tiles. Blocks [8192, 9984): packing.
// ---------------------------------------------------------------------------
__global__ __launch_bounds__(256) void prep_tr(const float* __restrict__ in,
                                               _Float16* __restrict__ out,
                                               const int* __restrict__ k0,
                                               const float* __restrict__ w0,
                                               const int* __restrict__ k1,
                                               const float* __restrict__ w1,
                                               const int* __restrict__ k2,
                                               const float* __restrict__ w2,
                                               unsigned int* __restrict__ po) {
    __shared__ float tile[32][33];
    if (blockIdx.x < TR_BLOCKS) {
        const int bx = (blockIdx.x & 511) * 32;      // IN_DIM base
        const int by = (blockIdx.x >> 9) * 32;       // BATCH base
        const int tx = threadIdx.x & 31;
        const int ty = threadIdx.x >> 5;             // 0..7
#pragma unroll
        for (int j = 0; j < 32; j += 8)
            tile[ty + j][tx] = in[(size_t)(by + ty + j) * IN_DIM + bx + tx];
        __syncthreads();
        const int r = threadIdx.x >> 3;              // 0..31
        const int c = (threadIdx.x & 7) * 4;
        half4v h;
        h[0] = (_Float16)tile[c + 0][r];
        h[1] = (_Float16)tile[c + 1][r];
        h[2] = (_Float16)tile[c + 2][r];
        h[3] = (_Float16)tile[c + 3][r];
        *(half4v*)(out + (size_t)(bx + r) * BATCH + by + c) = h;
    } else {
        const int t = (blockIdx.x - TR_BLOCKS) * 256 + threadIdx.x;
        int idx; float wv;
        if (t < N0) {
            idx = k0[t];            wv = w0[t];
        } else if (t < N0 + N1) {
            idx = k1[t - N0];       wv = w1[t - N0];
        } else {
            idx = k2[t - N0 - N1];  wv = w2[t - N0 - N1];
        }
        const unsigned short hb = __builtin_bit_cast(unsigned short, (_Float16)wv);
        po[t] = (unsigned int)(unsigned short)idx | ((unsigned int)hb << 16);
    }
}

// ---------------------------------------------------------------------------
// L0: R8's proven form. 1 feature x 64-batch chunk per wave, 4 waves/block,
// chunk = bid&7 (XCD-aligned by round-robin dispatch), packed dword s_loads,
// 128B/wave gathers. Slab 2MB + packed 1MB fits a 4MB XCD L2.
// ---------------------------------------------------------------------------
__global__ __launch_bounds__(256) void lcn_p4(const _Float16* __restrict__ xt,
                                              const unsigned int* __restrict__ packed,
                                              const float* __restrict__ bias,
                                              _Float16* __restrict__ yt) {
    const int lane = threadIdx.x & 63;
    const int wv   = __builtin_amdgcn_readfirstlane(threadIdx.x >> 6); // SGPR
    const int d    = (blockIdx.x >> 3) * 4 + wv;                       // scalar
    const int b    = (blockIdx.x & 7) * 64 + lane;
    const unsigned int* kp = packed + (size_t)d * KNN;
    const _Float16*     xb = xt + b;
    float acc = 0.f;
#pragma unroll
    for (int k = 0; k < KNN; ++k) {
        const unsigned int u = kp[k];                    // s_load dword
        const int idx = (int)(u & 0xffffu);
        const _Float16 hw =
            __builtin_bit_cast(_Float16, (unsigned short)(u >> 16));
        acc += (float)hw * (float)xb[(size_t)idx * BATCH];  // 128B/wave gather
    }
    acc = fmaxf(acc + bias[d], 0.f);
    yt[(size_t)d * BATCH + b] = (_Float16)acc;
}

// ---------------------------------------------------------------------------
// L1/L2: chunk=128, lane loads half2 -> 256B/wave requests (2x bytes/request
// at the same request rate, if the request-path model is right).
// Slab = prev_dim*128*2B <= 2MB fits L2; chunk = bid&3, XCD x serves x&3.
// ---------------------------------------------------------------------------
__global__ __launch_bounds__(256) void lcn_p4w(const _Float16* __restrict__ xt,
                                               const unsigned int* __restrict__ packed,
                                               const float* __restrict__ bias,
                                               _Float16* __restrict__ yt) {
    const int lane = threadIdx.x & 63;
    const int wv   = __builtin_amdgcn_readfirstlane(threadIdx.x >> 6); // SGPR
    const int d    = (blockIdx.x >> 2) * 4 + wv;                       // scalar
    const int b    = (blockIdx.x & 3) * 128 + 2 * lane;
    const unsigned int* kp = packed + (size_t)d * KNN;
    const _Float16*     xb = xt + b;
    float ax = 0.f, ay = 0.f;
#pragma unroll
    for (int k = 0; k < KNN; ++k) {
        const unsigned int u = kp[k];                    // s_load dword
        const int idx = (int)(u & 0xffffu);
        const float hw =
            (float)__builtin_bit_cast(_Float16, (unsigned short)(u >> 16));
        const half2v v = *(const half2v*)(xb + (size_t)idx * BATCH);  // 256B/wave
        ax += hw * (float)v[0];
        ay += hw * (float)v[1];
    }
    const float bv = bias[d];
    half2v r;
    r[0] = (_Float16)fmaxf(ax + bv, 0.f);
    r[1] = (_Float16)fmaxf(ay + bv, 0.f);
    *(half2v*)(yt + (size_t)d * BATCH + b) = r;
}

// ---------------------------------------------------------------------------
// FC stage 1, LDS-staged: y2t read ONCE (2MB logical instead of 32MB).
// Block (r = bid>>3: d-range of 256, c = bid&7: batch chunk of 64).
// Stage tile [256 d][64 b] (32KB LDS), wave w computes o in {4w..4w+3}.
// ---------------------------------------------------------------------------
__global__ __launch_bounds__(256) void fc_lds(const _Float16* __restrict__ y2t,
                                              const float* __restrict__ fcw,
                                              float* __restrict__ part) {
    __shared__ _Float16 ty[256][64];
    const int r  = blockIdx.x >> 3;
    const int c  = blockIdx.x & 7;
    const int rr = threadIdx.x >> 4;         // 0..15
    const int c4 = (threadIdx.x & 15) * 4;   // 0..60
#pragma unroll
    for (int j = 0; j < 16; ++j) {
        const int dl = j * 16 + rr;
        *(half4v*)&ty[dl][c4] =
            *(const half4v*)(y2t + (size_t)(r * 256 + dl) * BATCH + c * 64 + c4);
    }
    __syncthreads();
    const int b  = threadIdx.x & 63;
    const int wv = __builtin_amdgcn_readfirstlane(threadIdx.x >> 6);   // SGPR
    const float* fw = fcw + (size_t)(r * 256) * 16 + wv * 4;
    float a0 = 0.f, a1 = 0.f, a2 = 0.f, a3 = 0.f;
#pragma unroll 4
    for (int dl = 0; dl < 256; ++dl) {
        const float v = (float)ty[dl][b];
        a0 += v * fw[dl * 16 + 0];           // s_load (wave-uniform)
        a1 += v * fw[dl * 16 + 1];
        a2 += v * fw[dl * 16 + 2];
        a3 += v * fw[dl * 16 + 3];
    }
    const int bb = c * 64 + b;
    float* pp = part + ((size_t)bb * 16 + wv * 4) * 8 + r;
    pp[0]  = a0;
    pp[8]  = a1;
    pp[16] = a2;
    pp[24] = a3;
}

__global__ __launch_bounds__(256) void fc_final(const float* __restrict__ part,
                                                const float* __restrict__ fcb,
                                                float* __restrict__ out) {
    const int t = blockIdx.x * 256 + threadIdx.x;       // 0..8191
    const float4 p0 = *(const float4*)(part + (size_t)t * 8);
    const float4 p1 = *(const float4*)(part + (size_t)t * 8 + 4);
    out[t] = ((p0.x + p0.y) + (p0.z + p0.w)) + ((p1.x + p1.y) + (p1.z + p1.w))
             + fcb[t & 15];
}

extern "C" void kernel_launch(void* const* d_in, const int* in_sizes, int n_in,
                              void* d_out, int out_size, void* d_ws, size_t ws_size,
                              hipStream_t stream) {
    // setup_inputs() order: x, w0,b0,knn0, w1,b1,knn1, w2,b2,knn2, fc_w, fc_b
    const float* x    = (const float*)d_in[0];
    const float* w0   = (const float*)d_in[1];
    const float* b0   = (const float*)d_in[2];
    const int*   knn0 = (const int*)  d_in[3];
    const float* w1   = (const float*)d_in[4];
    const float* b1   = (const float*)d_in[5];
    const int*   knn1 = (const int*)  d_in[6];
    const float* w2   = (const float*)d_in[7];
    const float* b2   = (const float*)d_in[8];
    const int*   knn2 = (const int*)  d_in[9];
    const float* fcw  = (const float*)d_in[10];
    const float* fcb  = (const float*)d_in[11];
    float* out = (float*)d_out;

    // Workspace:
    //   xt   @  0 MB : 16 MB    y0t @ 16 MB : 8 MB
    //   y1t  @ 24 MB :  4 MB    y2t @ 28 MB : 2 MB
    //   part @ 30 MB : 256 KB   packed @ 30.5 MB : 1.75 MB
    char* ws = (char*)d_ws;
    _Float16*     xt   = (_Float16*)(ws);
    _Float16*     y0t  = (_Float16*)(ws + ((size_t)16 << 20));
    _Float16*     y1t  = (_Float16*)(ws + ((size_t)24 << 20));
    _Float16*     y2t  = (_Float16*)(ws + ((size_t)28 << 20));
    float*        part = (float*)   (ws + ((size_t)30 << 20));
    unsigned int* po   = (unsigned int*)(ws + ((size_t)30 << 20) + ((size_t)512 << 10));

    prep_tr<<<TR_BLOCKS + PREP_BLOCKS, 256, 0, stream>>>(x, xt, knn0, w0, knn1,
                                                         w1, knn2, w2, po);
    // L0: chunk=64 (proven), L1/L2: chunk=128, 256B requests.
    lcn_p4 <<<(8192 / 4) * 8, 256, 0, stream>>>(xt,  po,           b0, y0t);
    lcn_p4w<<<(4096 / 4) * 4, 256, 0, stream>>>(y0t, po + N0,      b1, y1t);
    lcn_p4w<<<(2048 / 4) * 4, 256, 0, stream>>>(y1t, po + N0 + N1, b2, y2t);
    fc_lds<<<64, 256, 0, stream>>>(y2t, fcw, part);
    fc_final<<<32, 256, 0, stream>>>(part, fcb, out);
}